// Round 1
// baseline (529.907 us; speedup 1.0000x reference)
//
#include <hip/hip_runtime.h>
#include <math.h>

// ContrastiveLoss: N=8192 samples, C=512 features, NC=100 classes, MARGIN=1.0
// loss = (sum_{i!=j, same} d_ij + sum_{i!=j, diff} hinge(1 - sqrt(d_ij))^2) / (2*N*(N-1))
// d_ij = |xi|^2 + |xj|^2 - 2 xi.xj, clamped at 0.
//
// Round 1: fp32 LDS-tiled pairwise kernel, upper-triangular blocks (x2 weight
// for off-diagonal), fused loss epilogue, deterministic 2-stage reduction.

static constexpr int   Nn   = 8192;
static constexpr int   Cc   = 512;
static constexpr float MRG  = 1.0f;
static constexpr int   BM   = 64;                       // tile rows/cols
static constexpr int   BK   = 32;                       // K chunk
static constexpr int   NBLK = Nn / BM;                  // 128 block rows
static constexpr int   NPAIRS = NBLK * (NBLK + 1) / 2;  // 8256 triangular blocks
static constexpr int   LSTR = 68;                       // LDS stride (floats), 16B-aligned rows, pad vs 64

// ---------------------------------------------------------------- sq[i] = |x_i|^2
__global__ __launch_bounds__(256) void sq_kernel(const float* __restrict__ f,
                                                 float* __restrict__ sq) {
    const int wave = threadIdx.x >> 6;   // 0..3
    const int lane = threadIdx.x & 63;
    const int row  = blockIdx.x * 4 + wave;
    const float4* rp = reinterpret_cast<const float4*>(f + (size_t)row * Cc);
    float4 v0 = rp[lane * 2 + 0];
    float4 v1 = rp[lane * 2 + 1];
    float s = v0.x * v0.x + v0.y * v0.y + v0.z * v0.z + v0.w * v0.w +
              v1.x * v1.x + v1.y * v1.y + v1.z * v1.z + v1.w * v1.w;
    #pragma unroll
    for (int off = 32; off > 0; off >>= 1) s += __shfl_down(s, off, 64);
    if (lane == 0) sq[row] = s;
}

// ---------------------------------------------------------------- main pairwise tile
__global__ __launch_bounds__(256) void pair_kernel(const float* __restrict__ f,
                                                   const int* __restrict__ tgt,
                                                   const float* __restrict__ sq,
                                                   double* __restrict__ partials) {
    // linear block id -> (br, bc) with br <= bc  (upper triangle)
    int rem = blockIdx.x;
    int br = 0;
    while (rem >= NBLK - br) { rem -= NBLK - br; ++br; }
    const int bc = br + rem;

    __shared__ float As[BK][LSTR];   // transposed: As[k][row]
    __shared__ float Bs[BK][LSTR];   // transposed: Bs[k][col]
    __shared__ float red[256];

    const int tid  = threadIdx.x;
    const int tx   = tid & 15;       // col group
    const int ty   = tid >> 4;       // row group
    const int row0 = ty * 4;
    const int col0 = tx * 4;

    const float* abase = f + (size_t)br * BM * Cc;
    const float* bbase = f + (size_t)bc * BM * Cc;

    const int r0 = tid >> 3;         // 0..31 (staging row)
    const int kq = tid & 7;          // 0..7  (staging k-quad)
    const int kb = kq * 4;

    float acc[4][4] = {};

    for (int k0 = 0; k0 < Cc; k0 += BK) {
        // issue global loads early (coalesced: 8 lanes cover one row's 32 floats)
        float4 a0 = *reinterpret_cast<const float4*>(abase + (size_t)(r0)      * Cc + k0 + kb);
        float4 a1 = *reinterpret_cast<const float4*>(abase + (size_t)(r0 + 32) * Cc + k0 + kb);
        float4 b0 = *reinterpret_cast<const float4*>(bbase + (size_t)(r0)      * Cc + k0 + kb);
        float4 b1 = *reinterpret_cast<const float4*>(bbase + (size_t)(r0 + 32) * Cc + k0 + kb);

        __syncthreads();   // previous chunk's compute done before overwrite
        As[kb + 0][r0]      = a0.x; As[kb + 1][r0]      = a0.y;
        As[kb + 2][r0]      = a0.z; As[kb + 3][r0]      = a0.w;
        As[kb + 0][r0 + 32] = a1.x; As[kb + 1][r0 + 32] = a1.y;
        As[kb + 2][r0 + 32] = a1.z; As[kb + 3][r0 + 32] = a1.w;
        Bs[kb + 0][r0]      = b0.x; Bs[kb + 1][r0]      = b0.y;
        Bs[kb + 2][r0]      = b0.z; Bs[kb + 3][r0]      = b0.w;
        Bs[kb + 0][r0 + 32] = b1.x; Bs[kb + 1][r0 + 32] = b1.y;
        Bs[kb + 2][r0 + 32] = b1.z; Bs[kb + 3][r0 + 32] = b1.w;
        __syncthreads();

        #pragma unroll
        for (int k = 0; k < BK; ++k) {
            float4 av = *reinterpret_cast<const float4*>(&As[k][row0]);
            float4 bv = *reinterpret_cast<const float4*>(&Bs[k][col0]);
            acc[0][0] = fmaf(av.x, bv.x, acc[0][0]);
            acc[0][1] = fmaf(av.x, bv.y, acc[0][1]);
            acc[0][2] = fmaf(av.x, bv.z, acc[0][2]);
            acc[0][3] = fmaf(av.x, bv.w, acc[0][3]);
            acc[1][0] = fmaf(av.y, bv.x, acc[1][0]);
            acc[1][1] = fmaf(av.y, bv.y, acc[1][1]);
            acc[1][2] = fmaf(av.y, bv.z, acc[1][2]);
            acc[1][3] = fmaf(av.y, bv.w, acc[1][3]);
            acc[2][0] = fmaf(av.z, bv.x, acc[2][0]);
            acc[2][1] = fmaf(av.z, bv.y, acc[2][1]);
            acc[2][2] = fmaf(av.z, bv.z, acc[2][2]);
            acc[2][3] = fmaf(av.z, bv.w, acc[2][3]);
            acc[3][0] = fmaf(av.w, bv.x, acc[3][0]);
            acc[3][1] = fmaf(av.w, bv.y, acc[3][1]);
            acc[3][2] = fmaf(av.w, bv.z, acc[3][2]);
            acc[3][3] = fmaf(av.w, bv.w, acc[3][3]);
        }
    }

    // ------------------------------------------------------------ fused loss epilogue
    const int gi = br * BM + row0;
    const int gj = bc * BM + col0;
    float sqi[4], sqj[4];
    int   ti_[4], tj_[4];
    #pragma unroll
    for (int m = 0; m < 4; ++m) { sqi[m] = sq[gi + m]; ti_[m] = tgt[gi + m]; }
    #pragma unroll
    for (int n = 0; n < 4; ++n) { sqj[n] = sq[gj + n]; tj_[n] = tgt[gj + n]; }

    float pos = 0.f, neg = 0.f;
    #pragma unroll
    for (int m = 0; m < 4; ++m) {
        #pragma unroll
        for (int n = 0; n < 4; ++n) {
            if (gi + m == gj + n) continue;          // diagonal masked
            float d = fmaxf(sqi[m] + sqj[n] - 2.0f * acc[m][n], 0.0f);
            if (ti_[m] == tj_[n]) {
                pos += d;
            } else {
                float tmp = (d > 0.0f) ? (MRG - sqrtf(d)) : MRG;
                if (tmp > 0.0f) neg += tmp * tmp;
            }
        }
    }
    const float w = (br == bc) ? 1.0f : 2.0f;        // triangle: off-diag counts twice
    red[tid] = w * (pos + neg);
    __syncthreads();
    #pragma unroll
    for (int st = 128; st > 0; st >>= 1) {
        if (tid < st) red[tid] += red[tid + st];
        __syncthreads();
    }
    if (tid == 0) partials[blockIdx.x] = (double)red[0];
}

// ---------------------------------------------------------------- final reduction
__global__ __launch_bounds__(256) void finish_kernel(const double* __restrict__ partials,
                                                     float* __restrict__ out) {
    __shared__ double red[256];
    double s = 0.0;
    for (int i = threadIdx.x; i < NPAIRS; i += 256) s += partials[i];
    red[threadIdx.x] = s;
    __syncthreads();
    #pragma unroll
    for (int st = 128; st > 0; st >>= 1) {
        if (threadIdx.x < st) red[threadIdx.x] += red[threadIdx.x + st];
        __syncthreads();
    }
    if (threadIdx.x == 0) {
        const double t = (double)Nn * (double)(Nn - 1);
        out[0] = (float)(red[0] / (2.0 * t));
    }
}

// ---------------------------------------------------------------- launch
extern "C" void kernel_launch(void* const* d_in, const int* in_sizes, int n_in,
                              void* d_out, int out_size, void* d_ws, size_t ws_size,
                              hipStream_t stream) {
    const float* f   = (const float*)d_in[0];
    const int*   tgt = (const int*)d_in[1];
    float*       out = (float*)d_out;

    float*  sq       = (float*)d_ws;                                   // 32 KB
    double* partials = (double*)((char*)d_ws + (size_t)Nn * sizeof(float)); // 66 KB

    hipLaunchKernelGGL(sq_kernel,     dim3(Nn / 4),  dim3(256), 0, stream, f, sq);
    hipLaunchKernelGGL(pair_kernel,   dim3(NPAIRS),  dim3(256), 0, stream, f, tgt, sq, partials);
    hipLaunchKernelGGL(finish_kernel, dim3(1),       dim3(256), 0, stream, partials, out);
}

// Round 2
// 93.131 us; speedup vs baseline: 5.6899x; 5.6899x over previous
//
#include <hip/hip_runtime.h>
#include <math.h>

// ContrastiveLoss: N=8192, C=512, NC=100, MARGIN=1.0
// loss = (sum_{i!=j,same} d_ij + sum_{i!=j,diff} max(0, 1-sqrt(d_ij))^2) / (2*N*(N-1))
// d_ij = |xi|^2+|xj|^2-2 xi.xj (clamped at 0).
//
// Round 2: bf16 MFMA Gram (16x16x32), 128x128 triangular tiles, XOR-swizzled
// LDS (T2), fused loss epilogue, fp32 |x|^2. Fallback to round-1 fp32 path if
// workspace is too small for the bf16 copy.

static constexpr int   Nn  = 8192;
static constexpr int   Cc  = 512;
static constexpr float MRG = 1.0f;

// ---- mfma config ----
static constexpr int BM2     = 128;
static constexpr int BK2     = 64;
static constexpr int NBLK2   = Nn / BM2;                  // 64
static constexpr int NPAIRS2 = NBLK2 * (NBLK2 + 1) / 2;   // 2080

// ---- fp32 fallback config (round 1) ----
static constexpr int BM1     = 64;
static constexpr int BK1     = 32;
static constexpr int NBLK1   = Nn / BM1;                  // 128
static constexpr int NPAIRS1 = NBLK1 * (NBLK1 + 1) / 2;   // 8256
static constexpr int LSTR    = 68;

typedef __attribute__((ext_vector_type(8))) short short8v;  // 8 bf16 (4 VGPRs)
typedef __attribute__((ext_vector_type(4))) float f32x4;

// ---------------------------------------------------------------- fp32 -> bf16 (RNE)
static __device__ inline unsigned short f2bf(float x) {
    unsigned u = __float_as_uint(x);
    unsigned rnd = 0x7FFFu + ((u >> 16) & 1u);
    return (unsigned short)((u + rnd) >> 16);
}

__global__ __launch_bounds__(256) void cvt_kernel(const float* __restrict__ f,
                                                  unsigned short* __restrict__ fb) {
    const int i = (blockIdx.x * 256 + threadIdx.x) * 8;
    float4 v0 = *reinterpret_cast<const float4*>(f + i);
    float4 v1 = *reinterpret_cast<const float4*>(f + i + 4);
    short8v o;
    o[0] = (short)f2bf(v0.x); o[1] = (short)f2bf(v0.y);
    o[2] = (short)f2bf(v0.z); o[3] = (short)f2bf(v0.w);
    o[4] = (short)f2bf(v1.x); o[5] = (short)f2bf(v1.y);
    o[6] = (short)f2bf(v1.z); o[7] = (short)f2bf(v1.w);
    *reinterpret_cast<short8v*>(fb + i) = o;
}

// ---------------------------------------------------------------- sq[i] = |x_i|^2 (fp32)
__global__ __launch_bounds__(256) void sq_kernel(const float* __restrict__ f,
                                                 float* __restrict__ sq) {
    const int wave = threadIdx.x >> 6;
    const int lane = threadIdx.x & 63;
    const int row  = blockIdx.x * 4 + wave;
    const float4* rp = reinterpret_cast<const float4*>(f + (size_t)row * Cc);
    float4 v0 = rp[lane * 2 + 0];
    float4 v1 = rp[lane * 2 + 1];
    float s = v0.x * v0.x + v0.y * v0.y + v0.z * v0.z + v0.w * v0.w +
              v1.x * v1.x + v1.y * v1.y + v1.z * v1.z + v1.w * v1.w;
    #pragma unroll
    for (int off = 32; off > 0; off >>= 1) s += __shfl_down(s, off, 64);
    if (lane == 0) sq[row] = s;
}

// ---------------------------------------------------------------- MFMA pairwise tile
__global__ __launch_bounds__(256) void pair_mfma(const unsigned short* __restrict__ fb,
                                                 const int* __restrict__ tgt,
                                                 const float* __restrict__ sq,
                                                 double* __restrict__ partials) {
    // linear block id -> (br, bc), br <= bc (upper triangle of 64x64 blocks)
    int rem = blockIdx.x, br = 0;
    while (rem >= NBLK2 - br) { rem -= NBLK2 - br; ++br; }
    const int bc = br + rem;

    __shared__ unsigned short As[BM2 * BK2];   // [row][k], XOR-swizzled bytes
    __shared__ unsigned short Bs[BM2 * BK2];
    __shared__ float red[256];

    const int tid  = threadIdx.x;
    const int lane = tid & 63;
    const int wid  = tid >> 6;
    const int wr   = wid >> 1;     // wave row 0..1 (64-row slab)
    const int wc   = wid & 1;      // wave col 0..1 (64-col slab)

    // staging: thread covers 16B (8 bf16); 256 threads = 32 rows x 128B per pass
    const int srow  = tid >> 3;    // 0..31
    const int kslot = tid & 7;     // 0..7
    const unsigned short* ga = fb + (size_t)(br * BM2) * Cc;
    const unsigned short* gb = fb + (size_t)(bc * BM2) * Cc;

    char* AsB = (char*)As;
    char* BsB = (char*)Bs;

    const f32x4 zero = {0.f, 0.f, 0.f, 0.f};
    f32x4 acc[4][4];
    #pragma unroll
    for (int mf = 0; mf < 4; ++mf)
        #pragma unroll
        for (int nf = 0; nf < 4; ++nf) acc[mf][nf] = zero;

    for (int k0 = 0; k0 < Cc; k0 += BK2) {
        short8v la[4], lb[4];
        #pragma unroll
        for (int p = 0; p < 4; ++p) {
            const int row = p * 32 + srow;
            la[p] = *reinterpret_cast<const short8v*>(ga + (size_t)row * Cc + k0 + kslot * 8);
            lb[p] = *reinterpret_cast<const short8v*>(gb + (size_t)row * Cc + k0 + kslot * 8);
        }
        __syncthreads();   // previous chunk's compute done before overwrite
        #pragma unroll
        for (int p = 0; p < 4; ++p) {
            const int row  = p * 32 + srow;
            const int byte = row * 128 + ((kslot * 16) ^ ((row & 7) << 4));
            *reinterpret_cast<short8v*>(AsB + byte) = la[p];
            *reinterpret_cast<short8v*>(BsB + byte) = lb[p];
        }
        __syncthreads();

        #pragma unroll
        for (int ks = 0; ks < 2; ++ks) {
            short8v a[4], b[4];
            #pragma unroll
            for (int mf = 0; mf < 4; ++mf) {
                const int row  = wr * 64 + mf * 16 + (lane & 15);
                const int byte = row * 128 + ((ks * 64 + (lane >> 4) * 16) ^ ((row & 7) << 4));
                a[mf] = *reinterpret_cast<const short8v*>(AsB + byte);
            }
            #pragma unroll
            for (int nf = 0; nf < 4; ++nf) {
                const int row  = wc * 64 + nf * 16 + (lane & 15);
                const int byte = row * 128 + ((ks * 64 + (lane >> 4) * 16) ^ ((row & 7) << 4));
                b[nf] = *reinterpret_cast<const short8v*>(BsB + byte);
            }
            #pragma unroll
            for (int mf = 0; mf < 4; ++mf)
                #pragma unroll
                for (int nf = 0; nf < 4; ++nf)
                    acc[mf][nf] = __builtin_amdgcn_mfma_f32_16x16x32_bf16(
                        a[mf], b[nf], acc[mf][nf], 0, 0, 0);
        }
    }

    // ------------------------------------------------------------ fused loss epilogue
    // C/D layout: col = lane&15, row = (lane>>4)*4 + reg  [m89/m91]
    const int gi0 = br * BM2 + wr * 64;
    const int gj0 = bc * BM2 + wc * 64;

    float sqi[16]; int ti[16];
    #pragma unroll
    for (int mf = 0; mf < 4; ++mf)
        #pragma unroll
        for (int j = 0; j < 4; ++j) {
            const int r = gi0 + mf * 16 + (lane >> 4) * 4 + j;
            sqi[mf * 4 + j] = sq[r];
            ti[mf * 4 + j]  = tgt[r];
        }
    float sqj[4]; int tj[4];
    #pragma unroll
    for (int nf = 0; nf < 4; ++nf) {
        const int c = gj0 + nf * 16 + (lane & 15);
        sqj[nf] = sq[c];
        tj[nf]  = tgt[c];
    }

    float pos = 0.f, neg = 0.f;
    #pragma unroll
    for (int mf = 0; mf < 4; ++mf)
        #pragma unroll
        for (int nf = 0; nf < 4; ++nf)
            #pragma unroll
            for (int j = 0; j < 4; ++j) {
                const int r = gi0 + mf * 16 + (lane >> 4) * 4 + j;
                const int c = gj0 + nf * 16 + (lane & 15);
                const float d = fmaxf(sqi[mf * 4 + j] + sqj[nf] - 2.0f * acc[mf][nf][j], 0.0f);
                if (r != c) {
                    if (ti[mf * 4 + j] == tj[nf]) {
                        pos += d;
                    } else if (d < 1.0f) {        // hinge active iff sqrt(d) < margin
                        const float t = MRG - sqrtf(d);
                        neg += t * t;
                    }
                }
            }

    const float w = (br == bc) ? 1.0f : 2.0f;
    red[tid] = w * (pos + neg);
    __syncthreads();
    #pragma unroll
    for (int st = 128; st > 0; st >>= 1) {
        if (tid < st) red[tid] += red[tid + st];
        __syncthreads();
    }
    if (tid == 0) partials[blockIdx.x] = (double)red[0];
}

// ---------------------------------------------------------------- fp32 fallback (round 1)
__global__ __launch_bounds__(256) void pair_fp32(const float* __restrict__ f,
                                                 const int* __restrict__ tgt,
                                                 const float* __restrict__ sq,
                                                 double* __restrict__ partials) {
    int rem = blockIdx.x, br = 0;
    while (rem >= NBLK1 - br) { rem -= NBLK1 - br; ++br; }
    const int bc = br + rem;

    __shared__ float As[BK1][LSTR];
    __shared__ float Bs[BK1][LSTR];
    __shared__ float red[256];

    const int tid  = threadIdx.x;
    const int tx   = tid & 15;
    const int ty   = tid >> 4;
    const int row0 = ty * 4;
    const int col0 = tx * 4;

    const float* abase = f + (size_t)br * BM1 * Cc;
    const float* bbase = f + (size_t)bc * BM1 * Cc;

    const int r0 = tid >> 3;
    const int kb = (tid & 7) * 4;

    float acc[4][4] = {};

    for (int k0 = 0; k0 < Cc; k0 += BK1) {
        float4 a0 = *reinterpret_cast<const float4*>(abase + (size_t)(r0)      * Cc + k0 + kb);
        float4 a1 = *reinterpret_cast<const float4*>(abase + (size_t)(r0 + 32) * Cc + k0 + kb);
        float4 b0 = *reinterpret_cast<const float4*>(bbase + (size_t)(r0)      * Cc + k0 + kb);
        float4 b1 = *reinterpret_cast<const float4*>(bbase + (size_t)(r0 + 32) * Cc + k0 + kb);
        __syncthreads();
        As[kb + 0][r0]      = a0.x; As[kb + 1][r0]      = a0.y;
        As[kb + 2][r0]      = a0.z; As[kb + 3][r0]      = a0.w;
        As[kb + 0][r0 + 32] = a1.x; As[kb + 1][r0 + 32] = a1.y;
        As[kb + 2][r0 + 32] = a1.z; As[kb + 3][r0 + 32] = a1.w;
        Bs[kb + 0][r0]      = b0.x; Bs[kb + 1][r0]      = b0.y;
        Bs[kb + 2][r0]      = b0.z; Bs[kb + 3][r0]      = b0.w;
        Bs[kb + 0][r0 + 32] = b1.x; Bs[kb + 1][r0 + 32] = b1.y;
        Bs[kb + 2][r0 + 32] = b1.z; Bs[kb + 3][r0 + 32] = b1.w;
        __syncthreads();
        #pragma unroll
        for (int k = 0; k < BK1; ++k) {
            float4 av = *reinterpret_cast<const float4*>(&As[k][row0]);
            float4 bv = *reinterpret_cast<const float4*>(&Bs[k][col0]);
            acc[0][0] = fmaf(av.x, bv.x, acc[0][0]);
            acc[0][1] = fmaf(av.x, bv.y, acc[0][1]);
            acc[0][2] = fmaf(av.x, bv.z, acc[0][2]);
            acc[0][3] = fmaf(av.x, bv.w, acc[0][3]);
            acc[1][0] = fmaf(av.y, bv.x, acc[1][0]);
            acc[1][1] = fmaf(av.y, bv.y, acc[1][1]);
            acc[1][2] = fmaf(av.y, bv.z, acc[1][2]);
            acc[1][3] = fmaf(av.y, bv.w, acc[1][3]);
            acc[2][0] = fmaf(av.z, bv.x, acc[2][0]);
            acc[2][1] = fmaf(av.z, bv.y, acc[2][1]);
            acc[2][2] = fmaf(av.z, bv.z, acc[2][2]);
            acc[2][3] = fmaf(av.z, bv.w, acc[2][3]);
            acc[3][0] = fmaf(av.w, bv.x, acc[3][0]);
            acc[3][1] = fmaf(av.w, bv.y, acc[3][1]);
            acc[3][2] = fmaf(av.w, bv.z, acc[3][2]);
            acc[3][3] = fmaf(av.w, bv.w, acc[3][3]);
        }
    }

    const int gi = br * BM1 + row0;
    const int gj = bc * BM1 + col0;
    float sqi[4], sqj[4];
    int   ti_[4], tj_[4];
    #pragma unroll
    for (int m = 0; m < 4; ++m) { sqi[m] = sq[gi + m]; ti_[m] = tgt[gi + m]; }
    #pragma unroll
    for (int n = 0; n < 4; ++n) { sqj[n] = sq[gj + n]; tj_[n] = tgt[gj + n]; }

    float pos = 0.f, neg = 0.f;
    #pragma unroll
    for (int m = 0; m < 4; ++m)
        #pragma unroll
        for (int n = 0; n < 4; ++n) {
            if (gi + m == gj + n) continue;
            float d = fmaxf(sqi[m] + sqj[n] - 2.0f * acc[m][n], 0.0f);
            if (ti_[m] == tj_[n]) pos += d;
            else if (d < 1.0f) { float t = MRG - sqrtf(d); neg += t * t; }
        }
    const float w = (br == bc) ? 1.0f : 2.0f;
    red[tid] = w * (pos + neg);
    __syncthreads();
    #pragma unroll
    for (int st = 128; st > 0; st >>= 1) {
        if (tid < st) red[tid] += red[tid + st];
        __syncthreads();
    }
    if (tid == 0) partials[blockIdx.x] = (double)red[0];
}

// ---------------------------------------------------------------- final reduction
__global__ __launch_bounds__(256) void finish_kernel(const double* __restrict__ partials,
                                                     float* __restrict__ out, int n) {
    __shared__ double red[256];
    double s = 0.0;
    for (int i = threadIdx.x; i < n; i += 256) s += partials[i];
    red[threadIdx.x] = s;
    __syncthreads();
    #pragma unroll
    for (int st = 128; st > 0; st >>= 1) {
        if (threadIdx.x < st) red[threadIdx.x] += red[threadIdx.x + st];
        __syncthreads();
    }
    if (threadIdx.x == 0) {
        const double t = (double)Nn * (double)(Nn - 1);
        out[0] = (float)(red[0] / (2.0 * t));
    }
}

// ---------------------------------------------------------------- launch
extern "C" void kernel_launch(void* const* d_in, const int* in_sizes, int n_in,
                              void* d_out, int out_size, void* d_ws, size_t ws_size,
                              hipStream_t stream) {
    const float* f   = (const float*)d_in[0];
    const int*   tgt = (const int*)d_in[1];
    float*       out = (float*)d_out;

    const size_t fbBytes = (size_t)Nn * Cc * 2;           // 8 MB bf16 copy
    const size_t sqBytes = (size_t)Nn * sizeof(float);    // 32 KB
    const size_t needed  = fbBytes + sqBytes + (size_t)NPAIRS2 * sizeof(double);

    if (ws_size >= needed) {
        unsigned short* fb = (unsigned short*)d_ws;
        float*  sq         = (float*)((char*)d_ws + fbBytes);
        double* partials   = (double*)((char*)d_ws + fbBytes + sqBytes);

        hipLaunchKernelGGL(cvt_kernel,    dim3(Nn * Cc / (8 * 256)), dim3(256), 0, stream, f, fb);
        hipLaunchKernelGGL(sq_kernel,     dim3(Nn / 4),              dim3(256), 0, stream, f, sq);
        hipLaunchKernelGGL(pair_mfma,     dim3(NPAIRS2),             dim3(256), 0, stream, fb, tgt, sq, partials);
        hipLaunchKernelGGL(finish_kernel, dim3(1),                   dim3(256), 0, stream, partials, out, NPAIRS2);
    } else {
        float*  sq       = (float*)d_ws;
        double* partials = (double*)((char*)d_ws + sqBytes);

        hipLaunchKernelGGL(sq_kernel,     dim3(Nn / 4),  dim3(256), 0, stream, f, sq);
        hipLaunchKernelGGL(pair_fp32,     dim3(NPAIRS1), dim3(256), 0, stream, f, tgt, sq, partials);
        hipLaunchKernelGGL(finish_kernel, dim3(1),       dim3(256), 0, stream, partials, out, NPAIRS1);
    }
}